// Round 15
// baseline (502.704 us; speedup 1.0000x reference)
//
#include <hip/hip_runtime.h>

#define N_NODES 100000
#define N_EDGES 800000
// IN=128, HID=256, OUT=128
#define SCAN_CHUNK 1024
#define SCAN_NB ((N_NODES + SCAN_CHUNK - 1) / SCAN_CHUNK)   // 98

typedef __attribute__((ext_vector_type(8))) short bf16x8;
typedef __attribute__((ext_vector_type(4))) float f32x4;

// ---------------- degree count (int atomics) ----------------
__global__ void count_int_k(const int* __restrict__ dst, int* __restrict__ cnt, int E) {
    int i = blockIdx.x * blockDim.x + threadIdx.x;
    if (i < E) atomicAdd(&cnt[dst[i]], 1);
}

// ---------------- scan pass 1 ----------------
__global__ __launch_bounds__(256) void scan1_k(const int* __restrict__ cnt,
                                               int* __restrict__ offs,
                                               int* __restrict__ bsums, int N) {
    __shared__ int s[256];
    int t = threadIdx.x;
    int base = blockIdx.x * SCAN_CHUNK + t * 4;
    int v0 = (base + 0 < N) ? cnt[base + 0] : 0;
    int v1 = (base + 1 < N) ? cnt[base + 1] : 0;
    int v2 = (base + 2 < N) ? cnt[base + 2] : 0;
    int v3 = (base + 3 < N) ? cnt[base + 3] : 0;
    int tsum = v0 + v1 + v2 + v3;
    s[t] = tsum;
    __syncthreads();
    for (int off = 1; off < 256; off <<= 1) {
        int val = (t >= off) ? s[t - off] : 0;
        __syncthreads();
        s[t] += val;
        __syncthreads();
    }
    int excl = s[t] - tsum;
    if (base + 0 < N) offs[base + 0] = excl;
    if (base + 1 < N) offs[base + 1] = excl + v0;
    if (base + 2 < N) offs[base + 2] = excl + v0 + v1;
    if (base + 3 < N) offs[base + 3] = excl + v0 + v1 + v2;
    if (t == 255) bsums[blockIdx.x] = s[255];
}

// ---------------- scan pass 2 ----------------
__global__ __launch_bounds__(256) void scan2_k(const int* __restrict__ bsums,
                                               int* __restrict__ boffs, int nb) {
    __shared__ int s[256];
    int t = threadIdx.x;
    int v = (t < nb) ? bsums[t] : 0;
    s[t] = v;
    __syncthreads();
    for (int off = 1; off < 256; off <<= 1) {
        int val = (t >= off) ? s[t - off] : 0;
        __syncthreads();
        s[t] += val;
        __syncthreads();
    }
    if (t < nb) boffs[t] = s[t] - v;
}

// ---------------- scan pass 3 ----------------
__global__ void scan3_k(int* __restrict__ offs, int* __restrict__ cursor,
                        const int* __restrict__ boffs, int N, int E) {
    int i = blockIdx.x * blockDim.x + threadIdx.x;
    if (i < N) {
        int v = offs[i] + boffs[i >> 10];
        offs[i] = v;
        cursor[i] = v;
    }
    if (i == 0) offs[N] = E;
}

// ---------------- bucket fill ----------------
__global__ void fill_k(const int* __restrict__ src, const int* __restrict__ dst,
                       int* __restrict__ cursor, int* __restrict__ perm, int E) {
    int e = blockIdx.x * blockDim.x + threadIdx.x;
    if (e < E) {
        int d = dst[e];
        int slot = atomicAdd(&cursor[d], 1);
        perm[slot] = src[e];
    }
}

// ---------------- split fp32 -> (bf16 hi, bf16 lo) ----------------
__device__ inline short2 cvt_split(float a) {
    unsigned u = __builtin_bit_cast(unsigned, a);
    unsigned r = u + 0x7FFF + ((u >> 16) & 1);
    unsigned short h = (unsigned short)(r >> 16);
    float hf = __builtin_bit_cast(float, (unsigned)h << 16);
    float l = a - hf;
    unsigned ul = __builtin_bit_cast(unsigned, l);
    unsigned rl = ul + 0x7FFF + ((ul >> 16) & 1);
    return make_short2((short)h, (short)(rl >> 16));
}

// ---------------- bulk PAIR16 conversion: 16 floats -> [16 hi | 16 lo] ----------------
__global__ __launch_bounds__(256) void cvt_pair_k(const float* __restrict__ in,
                                                  short* __restrict__ outp, int n16) {
    int i = blockIdx.x * blockDim.x + threadIdx.x;
    if (i >= n16) return;
    const float4* p = (const float4*)in + (long long)i * 4;
    bf16x8 h0, h1, l0, l1;
    short2 c;
#pragma unroll
    for (int q = 0; q < 2; ++q) {
        float4 v0 = p[q * 2], v1 = p[q * 2 + 1];
        bf16x8& hv = q ? h1 : h0;
        bf16x8& lv = q ? l1 : l0;
        c = cvt_split(v0.x); hv[0] = c.x; lv[0] = c.y;
        c = cvt_split(v0.y); hv[1] = c.x; lv[1] = c.y;
        c = cvt_split(v0.z); hv[2] = c.x; lv[2] = c.y;
        c = cvt_split(v0.w); hv[3] = c.x; lv[3] = c.y;
        c = cvt_split(v1.x); hv[4] = c.x; lv[4] = c.y;
        c = cvt_split(v1.y); hv[5] = c.x; lv[5] = c.y;
        c = cvt_split(v1.z); hv[6] = c.x; lv[6] = c.y;
        c = cvt_split(v1.w); hv[7] = c.x; lv[7] = c.y;
    }
    long long b = (long long)i * 32;
    *(bf16x8*)&outp[b]      = h0;
    *(bf16x8*)&outp[b + 8]  = h1;
    *(bf16x8*)&outp[b + 16] = l0;
    *(bf16x8*)&outp[b + 24] = l1;
}

// ---------------- gather-mean (float4/thread) -> pair16 bf16 ----------------
__global__ __launch_bounds__(256) void aggmean_k(const float* __restrict__ feat,
                                                 const int* __restrict__ perm,
                                                 const int* __restrict__ offs,
                                                 short* __restrict__ mp, int N) {
    int tid = threadIdx.x;
    int node = blockIdx.x * 8 + (tid >> 5);
    int q = tid & 31;                       // channels q*4..q*4+3
    if (node >= N) return;
    int beg = offs[node], end = offs[node + 1];
    float ax = 0, ay = 0, az = 0, aw = 0;
    float bx = 0, by = 0, bz = 0, bw = 0;
    int i = beg;
    for (; i + 1 < end; i += 2) {
        float4 v0 = ((const float4*)feat)[(long long)perm[i] * 32 + q];
        float4 v1 = ((const float4*)feat)[(long long)perm[i + 1] * 32 + q];
        ax += v0.x; ay += v0.y; az += v0.z; aw += v0.w;
        bx += v1.x; by += v1.y; bz += v1.z; bw += v1.w;
    }
    if (i < end) {
        float4 v0 = ((const float4*)feat)[(long long)perm[i] * 32 + q];
        ax += v0.x; ay += v0.y; az += v0.z; aw += v0.w;
    }
    float rc = 1.0f / fmaxf((float)(end - beg), 1.0f);
    short2 c0 = cvt_split((ax + bx) * rc);
    short2 c1 = cvt_split((ay + by) * rc);
    short2 c2 = cvt_split((az + bz) * rc);
    short2 c3 = cvt_split((aw + bw) * rc);
    // pair16 layout: group = q>>2 (32 shorts), within = (q&3)*4
    long long base = (long long)node * 256 + (q >> 2) * 32 + (q & 3) * 4;
    *(short4*)&mp[base]      = make_short4(c0.x, c1.x, c2.x, c3.x);
    *(short4*)&mp[base + 16] = make_short4(c0.y, c1.y, c2.y, c3.y);
}

// ---------------- layer-2 agg fused epilogue: out = mean(g) + r2 + b2l ----------------
__global__ __launch_bounds__(256) void aggout_k(const float* __restrict__ g,
                                                const int* __restrict__ perm,
                                                const int* __restrict__ offs,
                                                const float* __restrict__ r2,
                                                const float* __restrict__ b2l,
                                                float* __restrict__ out, int N) {
    int tid = threadIdx.x;
    int node = blockIdx.x * 8 + (tid >> 5);
    int q = tid & 31;
    if (node >= N) return;
    int beg = offs[node], end = offs[node + 1];
    float ax = 0, ay = 0, az = 0, aw = 0;
    float bx = 0, by = 0, bz = 0, bw = 0;
    int i = beg;
    for (; i + 1 < end; i += 2) {
        float4 v0 = ((const float4*)g)[(long long)perm[i] * 32 + q];
        float4 v1 = ((const float4*)g)[(long long)perm[i + 1] * 32 + q];
        ax += v0.x; ay += v0.y; az += v0.z; aw += v0.w;
        bx += v1.x; by += v1.y; bz += v1.z; bw += v1.w;
    }
    if (i < end) {
        float4 v0 = ((const float4*)g)[(long long)perm[i] * 32 + q];
        ax += v0.x; ay += v0.y; az += v0.z; aw += v0.w;
    }
    float rc = 1.0f / fmaxf((float)(end - beg), 1.0f);
    float4 rv = ((const float4*)r2)[(long long)node * 32 + q];
    float4 bv = ((const float4*)b2l)[q];
    float4 o;
    o.x = (ax + bx) * rc + rv.x + bv.x;
    o.y = (ay + by) * rc + rv.y + bv.y;
    o.z = (az + bz) * rc + rv.z + bv.z;
    o.w = (aw + bw) * rc + rv.w + bv.w;
    ((float4*)out)[(long long)node * 32 + q] = o;
}

// ---------------- async global->LDS, 16B/lane ----------------
__device__ inline void gload16(const void* g, void* l) {
    __builtin_amdgcn_global_load_lds(
        (const __attribute__((address_space(1))) unsigned int*)g,
        (__attribute__((address_space(3))) unsigned int*)l,
        16, 0, 0);
}

// ================= FUSED two-layer split-bf16 MFMA kernel =================
// Block = 64-row panel, FULL 256-col width. 512 threads = 8 waves
// (2 row-halves wm x 4 col-quarters wn), per-wave 32x64 = 2x4 16x16 frags.
// Phase 1: h = relu([mp|xp] @ [W1l|W1r]^T + b1), K=256, 8 stages BK=32.
//   h kept IN REGISTERS as bf16 hi/lo short4 pairs (never hits global).
// Phase 2: [g|r2] = h @ [W2l;W2r]^T, K2=256 = h-cols, 8 slices BK2=32.
//   Slice s owned by waves wn==s>>1: they ds_write their h-slice into Hs
//   (=As region): row r, k 8c+e at chunk c (hi: 0..3, lo: 4..7), slot
//   c^(r&7). All waves DMA-stage W2 slice (pair16, chunks hiC/hiC+2).
// LDS = As/Hs 8 KiB + Bs 32 KiB = 40 KiB.
__global__ __launch_bounds__(512, 4) void fused_k(
        const short* __restrict__ mp, const short* __restrict__ xp,
        const short* __restrict__ w1lp, const short* __restrict__ w1rp,
        const short* __restrict__ w2lp, const short* __restrict__ w2rp,
        const float* __restrict__ b1l,
        float* __restrict__ g, float* __restrict__ r2, int N) {
    __shared__ short As[64 * 64];    // 8 KiB, reused as Hs in phase 2
    __shared__ short Bs[256 * 64];   // 32 KiB

    const int m0 = blockIdx.x * 64;
    const int tid = threadIdx.x;
    const int lane = tid & 63;
    const int wid = tid >> 6;            // 0..7
    const int wm = wid >> 2, wn = wid & 3;
    const int lr = lane & 15, lg = lane >> 4;
    const int hiC = ((lg >> 1) << 2) | (lg & 1);   // pair16 hi chunk for k-chunk lg

    // DMA lane geometry
    const int r8 = lane >> 3;
    const int scs = lane & 7;
    const int k8s = scs ^ r8;

    // ================= phase 1 =================
    f32x4 acc1[2][4];
#pragma unroll
    for (int i = 0; i < 2; i++)
#pragma unroll
        for (int j = 0; j < 4; j++) acc1[i][j] = (f32x4)0.0f;

#pragma unroll
    for (int kt = 0; kt < 8; ++kt) {
        __syncthreads();
        const short* Asrc = (kt < 4) ? mp : xp;
        const short* Bsrc = (kt < 4) ? w1lp : w1rp;
        const int koff = (kt & 3) * 64;
        {   // A: 8 segs, 1 per wave (rows 0..63)
            int row = wid * 8 + r8;
            int gn = m0 + row;
            if (gn < N)
                gload16(Asrc + (long long)gn * 256 + koff + k8s * 8, &As[wid * 512]);
        }
#pragma unroll
        for (int it = 0; it < 4; ++it) {   // B: 32 segs (rows 0..255)
            int seg = wid * 4 + it;
            int row = seg * 8 + r8;
            gload16(Bsrc + (long long)row * 256 + koff + k8s * 8, &Bs[seg * 512]);
        }
        __syncthreads();

        bf16x8 bh[4], bl[4];
#pragma unroll
        for (int fc = 0; fc < 4; ++fc) {
            int c_ = wn * 64 + fc * 16 + lr;
            bh[fc] = *(const bf16x8*)&Bs[c_ * 64 + ((hiC    ) ^ (c_ & 7)) * 8];
            bl[fc] = *(const bf16x8*)&Bs[c_ * 64 + ((hiC + 2) ^ (c_ & 7)) * 8];
        }
#pragma unroll
        for (int fr = 0; fr < 2; ++fr) {
            int r_ = wm * 32 + fr * 16 + lr;
            bf16x8 ah = *(const bf16x8*)&As[r_ * 64 + ((hiC    ) ^ (r_ & 7)) * 8];
            bf16x8 al = *(const bf16x8*)&As[r_ * 64 + ((hiC + 2) ^ (r_ & 7)) * 8];
#pragma unroll
            for (int fc = 0; fc < 4; ++fc) {
                acc1[fr][fc] = __builtin_amdgcn_mfma_f32_16x16x32_bf16(al, bh[fc], acc1[fr][fc], 0, 0, 0);
                acc1[fr][fc] = __builtin_amdgcn_mfma_f32_16x16x32_bf16(ah, bl[fc], acc1[fr][fc], 0, 0, 0);
                acc1[fr][fc] = __builtin_amdgcn_mfma_f32_16x16x32_bf16(ah, bh[fc], acc1[fr][fc], 0, 0, 0);
            }
        }
    }

    // ---- epilogue 1: relu+bias, split to bf16 pairs, KEEP IN REGISTERS ----
    short4 hhi[2][4], hlo[2][4];
#pragma unroll
    for (int fc = 0; fc < 4; ++fc) {
        int col = wn * 64 + fc * 16 + lr;
        float bv = b1l[col];
#pragma unroll
        for (int fr = 0; fr < 2; ++fr) {
            short2 t0 = cvt_split(fmaxf(acc1[fr][fc][0] + bv, 0.0f));
            short2 t1 = cvt_split(fmaxf(acc1[fr][fc][1] + bv, 0.0f));
            short2 t2 = cvt_split(fmaxf(acc1[fr][fc][2] + bv, 0.0f));
            short2 t3 = cvt_split(fmaxf(acc1[fr][fc][3] + bv, 0.0f));
            hhi[fr][fc] = make_short4(t0.x, t1.x, t2.x, t3.x);
            hlo[fr][fc] = make_short4(t0.y, t1.y, t2.y, t3.y);
        }
    }

    // ================= phase 2 =================
    f32x4 acc2[2][4];
#pragma unroll
    for (int i = 0; i < 2; i++)
#pragma unroll
        for (int j = 0; j < 4; j++) acc2[i][j] = (f32x4)0.0f;

#pragma unroll
    for (int s = 0; s < 8; ++s) {
        __syncthreads();    // previous slice's readers done (s=0: phase-1 readers)
        // ---- producers: waves with wn == s>>1 write their h-slice into Hs(=As) ----
        if (wn == (s >> 1)) {
#pragma unroll
            for (int f2 = 0; f2 < 2; ++f2) {
                const int fco = (s & 1) * 2 + f2;        // fc owned, static
                const int chunkb = f2 * 2 + (lr >> 3);   // k-chunk 0..3 in slice
                const int el = lr & 7;
#pragma unroll
                for (int fr = 0; fr < 2; ++fr) {
                    int rb = wm * 32 + fr * 16 + lg * 4;
#define WR_H(J, COMP)                                                              \
                    {   int row = rb + J;                                          \
                        As[row * 64 + ((chunkb    ) ^ (row & 7)) * 8 + el] = hhi[fr][fco].COMP; \
                        As[row * 64 + ((chunkb + 4) ^ (row & 7)) * 8 + el] = hlo[fr][fco].COMP; }
                    WR_H(0, x) WR_H(1, y) WR_H(2, z) WR_H(3, w)
#undef WR_H
                }
            }
        }
        // ---- all waves: stage W2 k-slice (rows = out cols 0..255) ----
#pragma unroll
        for (int it = 0; it < 4; ++it) {
            int seg = wid * 4 + it;
            int c2 = seg * 8 + r8;
            const short* W = (c2 < 128) ? w2lp : w2rp;
            gload16(W + (long long)(c2 & 127) * 512 + s * 64 + k8s * 8, &Bs[seg * 512]);
        }
        __syncthreads();    // ds_writes visible + DMA drained

        // ---- compute: 24 MFMA/wave ----
        bf16x8 bh[4], bl[4];
#pragma unroll
        for (int fc = 0; fc < 4; ++fc) {
            int c_ = wn * 64 + fc * 16 + lr;
            bh[fc] = *(const bf16x8*)&Bs[c_ * 64 + ((hiC    ) ^ (c_ & 7)) * 8];
            bl[fc] = *(const bf16x8*)&Bs[c_ * 64 + ((hiC + 2) ^ (c_ & 7)) * 8];
        }
#pragma unroll
        for (int fr = 0; fr < 2; ++fr) {
            int r_ = wm * 32 + fr * 16 + lr;
            bf16x8 ah = *(const bf16x8*)&As[r_ * 64 + ((lg    ) ^ (r_ & 7)) * 8];
            bf16x8 al = *(const bf16x8*)&As[r_ * 64 + ((lg + 4) ^ (r_ & 7)) * 8];
#pragma unroll
            for (int fc = 0; fc < 4; ++fc) {
                acc2[fr][fc] = __builtin_amdgcn_mfma_f32_16x16x32_bf16(al, bh[fc], acc2[fr][fc], 0, 0, 0);
                acc2[fr][fc] = __builtin_amdgcn_mfma_f32_16x16x32_bf16(ah, bl[fc], acc2[fr][fc], 0, 0, 0);
                acc2[fr][fc] = __builtin_amdgcn_mfma_f32_16x16x32_bf16(ah, bh[fc], acc2[fr][fc], 0, 0, 0);
            }
        }
    }

    // ---- epilogue 2: fp32 stores to g / r2 ----
#pragma unroll
    for (int fc = 0; fc < 4; ++fc) {
        int col = wn * 64 + fc * 16 + lr;       // 0..255
        float* dp = (col < 128) ? g : r2;       // uniform per wn
        int dcol = col & 127;
#pragma unroll
        for (int fr = 0; fr < 2; ++fr) {
#pragma unroll
            for (int j = 0; j < 4; ++j) {
                int row = m0 + wm * 32 + fr * 16 + lg * 4 + j;
                if (row < N)
                    dp[(long long)row * 128 + dcol] = acc2[fr][fc][j];
            }
        }
    }
}

extern "C" void kernel_launch(void* const* d_in, const int* in_sizes, int n_in,
                              void* d_out, int out_size, void* d_ws, size_t ws_size,
                              hipStream_t stream) {
    const float* x   = (const float*)d_in[0];
    const int*   ei  = (const int*)d_in[1];     // [2, E]
    const float* W1l = (const float*)d_in[2];
    const float* b1l = (const float*)d_in[3];
    const float* W1r = (const float*)d_in[4];
    const float* W2l = (const float*)d_in[5];
    const float* b2l = (const float*)d_in[6];
    const float* W2r = (const float*)d_in[7];
    float* out = (float*)d_out;

    const int N = N_NODES, E = N_EDGES;
    const int* srcI = ei;
    const int* dstI = ei + E;

    char* ws = (char*)d_ws;
    size_t off = 0;
    auto alloc = [&](size_t bytes) {
        size_t o = off;
        off += (bytes + 511) & ~(size_t)511;
        return o;
    };
    size_t off_cnt   = alloc((size_t)N * 4);
    size_t off_offs  = alloc((size_t)(N + 1) * 4);
    size_t off_cur   = alloc((size_t)N * 4);
    size_t off_bsum  = alloc((size_t)SCAN_NB * 4);
    size_t off_boff  = alloc((size_t)SCAN_NB * 4);
    size_t off_perm  = alloc((size_t)E * 4);
    size_t off_xp    = alloc((size_t)N * 256 * 2);     // x pair16
    size_t off_mp    = alloc((size_t)N * 256 * 2);     // mean pair16; reused as g (fp32)
    size_t off_r2    = alloc((size_t)N * 128 * 4);     // fp32
    size_t off_w     = alloc((size_t)4 * 65536 * 2);   // 4 paired weights
    int*   cntI  = (int*)(ws + off_cnt);
    int*   offs  = (int*)(ws + off_offs);
    int*   cur   = (int*)(ws + off_cur);
    int*   bsum  = (int*)(ws + off_bsum);
    int*   boff  = (int*)(ws + off_boff);
    int*   perm  = (int*)(ws + off_perm);
    short* xp    = (short*)(ws + off_xp);
    short* mp    = (short*)(ws + off_mp);
    float* g     = (float*)(ws + off_mp);   // aliases mp: per-block row ranges disjoint,
                                            // each block reads only its own mp rows in
                                            // phase 1 before writing the same g rows
    float* r2    = (float*)(ws + off_r2);
    short* wbuf  = (short*)(ws + off_w);
    const int WSZ = 65536;                             // 256*128 elems paired
    short* w1lp = wbuf;            short* w1rp = wbuf + WSZ;
    short* w2lp = wbuf + 2 * WSZ;  short* w2rp = wbuf + 3 * WSZ;

    // ---- CSR build ----
    (void)hipMemsetAsync(cntI, 0, (size_t)N * 4, stream);
    count_int_k<<<(E + 255) / 256, 256, 0, stream>>>(dstI, cntI, E);
    scan1_k<<<SCAN_NB, 256, 0, stream>>>(cntI, offs, bsum, N);
    scan2_k<<<1, 256, 0, stream>>>(bsum, boff, SCAN_NB);
    scan3_k<<<(N + 255) / 256, 256, 0, stream>>>(offs, cur, boff, N, E);
    fill_k<<<(E + 255) / 256, 256, 0, stream>>>(srcI, dstI, cur, perm, E);

    // ---- pair16 conversions ----
    {
        int n16x = N * 8;                          // N*128/16
        cvt_pair_k<<<(n16x + 255) / 256, 256, 0, stream>>>(x, xp, n16x);
        int n16w = 256 * 128 / 16;                 // 2048
        cvt_pair_k<<<(n16w + 255) / 256, 256, 0, stream>>>(W1l, w1lp, n16w);
        cvt_pair_k<<<(n16w + 255) / 256, 256, 0, stream>>>(W1r, w1rp, n16w);
        cvt_pair_k<<<(n16w + 255) / 256, 256, 0, stream>>>(W2l, w2lp, n16w);
        cvt_pair_k<<<(n16w + 255) / 256, 256, 0, stream>>>(W2r, w2rp, n16w);
    }

    // ---- layer 1 aggregation ----
    aggmean_k<<<(N + 7) / 8, 256, 0, stream>>>(x, perm, offs, mp, N);

    // ---- fused layer1+layer2 GEMMs ----
    {
        int nblk = (N + 63) / 64;   // 1563
        fused_k<<<nblk, 512, 0, stream>>>(mp, xp, w1lp, w1rp, w2lp, w2rp,
                                          b1l, g, r2, N);
    }

    // ---- layer 2 aggregation + epilogue ----
    aggout_k<<<(N + 7) / 8, 256, 0, stream>>>(g, perm, offs, r2, b2l, out, N);
}

// Round 16
// 454.507 us; speedup vs baseline: 1.1060x; 1.1060x over previous
//
#include <hip/hip_runtime.h>

#define N_NODES 100000
#define N_EDGES 800000
// IN=128, HID=256, OUT=128
#define SCAN_CHUNK 1024
#define SCAN_NB ((N_NODES + SCAN_CHUNK - 1) / SCAN_CHUNK)   // 98

typedef __attribute__((ext_vector_type(8))) short bf16x8;
typedef __attribute__((ext_vector_type(4))) float f32x4;
typedef __attribute__((ext_vector_type(4))) unsigned u32x4;

// ---------------- degree count (int atomics) ----------------
__global__ void count_int_k(const int* __restrict__ dst, int* __restrict__ cnt, int E) {
    int i = blockIdx.x * blockDim.x + threadIdx.x;
    if (i < E) atomicAdd(&cnt[dst[i]], 1);
}

// ---------------- scan pass 1 ----------------
__global__ __launch_bounds__(256) void scan1_k(const int* __restrict__ cnt,
                                               int* __restrict__ offs,
                                               int* __restrict__ bsums, int N) {
    __shared__ int s[256];
    int t = threadIdx.x;
    int base = blockIdx.x * SCAN_CHUNK + t * 4;
    int v0 = (base + 0 < N) ? cnt[base + 0] : 0;
    int v1 = (base + 1 < N) ? cnt[base + 1] : 0;
    int v2 = (base + 2 < N) ? cnt[base + 2] : 0;
    int v3 = (base + 3 < N) ? cnt[base + 3] : 0;
    int tsum = v0 + v1 + v2 + v3;
    s[t] = tsum;
    __syncthreads();
    for (int off = 1; off < 256; off <<= 1) {
        int val = (t >= off) ? s[t - off] : 0;
        __syncthreads();
        s[t] += val;
        __syncthreads();
    }
    int excl = s[t] - tsum;
    if (base + 0 < N) offs[base + 0] = excl;
    if (base + 1 < N) offs[base + 1] = excl + v0;
    if (base + 2 < N) offs[base + 2] = excl + v0 + v1;
    if (base + 3 < N) offs[base + 3] = excl + v0 + v1 + v2;
    if (t == 255) bsums[blockIdx.x] = s[255];
}

// ---------------- scan pass 2 ----------------
__global__ __launch_bounds__(256) void scan2_k(const int* __restrict__ bsums,
                                               int* __restrict__ boffs, int nb) {
    __shared__ int s[256];
    int t = threadIdx.x;
    int v = (t < nb) ? bsums[t] : 0;
    s[t] = v;
    __syncthreads();
    for (int off = 1; off < 256; off <<= 1) {
        int val = (t >= off) ? s[t - off] : 0;
        __syncthreads();
        s[t] += val;
        __syncthreads();
    }
    if (t < nb) boffs[t] = s[t] - v;
}

// ---------------- scan pass 3 ----------------
__global__ void scan3_k(int* __restrict__ offs, int* __restrict__ cursor,
                        const int* __restrict__ boffs, int N, int E) {
    int i = blockIdx.x * blockDim.x + threadIdx.x;
    if (i < N) {
        int v = offs[i] + boffs[i >> 10];
        offs[i] = v;
        cursor[i] = v;
    }
    if (i == 0) offs[N] = E;
}

// ---------------- bucket fill ----------------
__global__ void fill_k(const int* __restrict__ src, const int* __restrict__ dst,
                       int* __restrict__ cursor, int* __restrict__ perm, int E) {
    int e = blockIdx.x * blockDim.x + threadIdx.x;
    if (e < E) {
        int d = dst[e];
        int slot = atomicAdd(&cursor[d], 1);
        perm[slot] = src[e];
    }
}

// ---------------- split fp32 -> (bf16 hi, bf16 lo) ----------------
__device__ inline short2 cvt_split(float a) {
    unsigned u = __builtin_bit_cast(unsigned, a);
    unsigned r = u + 0x7FFF + ((u >> 16) & 1);
    unsigned short h = (unsigned short)(r >> 16);
    float hf = __builtin_bit_cast(float, (unsigned)h << 16);
    float l = a - hf;
    unsigned ul = __builtin_bit_cast(unsigned, l);
    unsigned rl = ul + 0x7FFF + ((ul >> 16) & 1);
    return make_short2((short)h, (short)(rl >> 16));
}

// ---------------- bulk PAIR16 conversion: 16 floats -> [16 hi | 16 lo] ----------------
__global__ __launch_bounds__(256) void cvt_pair_k(const float* __restrict__ in,
                                                  short* __restrict__ outp, int n16) {
    int i = blockIdx.x * blockDim.x + threadIdx.x;
    if (i >= n16) return;
    const float4* p = (const float4*)in + (long long)i * 4;
    bf16x8 h0, h1, l0, l1;
    short2 c;
#pragma unroll
    for (int q = 0; q < 2; ++q) {
        float4 v0 = p[q * 2], v1 = p[q * 2 + 1];
        bf16x8& hv = q ? h1 : h0;
        bf16x8& lv = q ? l1 : l0;
        c = cvt_split(v0.x); hv[0] = c.x; lv[0] = c.y;
        c = cvt_split(v0.y); hv[1] = c.x; lv[1] = c.y;
        c = cvt_split(v0.z); hv[2] = c.x; lv[2] = c.y;
        c = cvt_split(v0.w); hv[3] = c.x; lv[3] = c.y;
        c = cvt_split(v1.x); hv[4] = c.x; lv[4] = c.y;
        c = cvt_split(v1.y); hv[5] = c.x; lv[5] = c.y;
        c = cvt_split(v1.z); hv[6] = c.x; lv[6] = c.y;
        c = cvt_split(v1.w); hv[7] = c.x; lv[7] = c.y;
    }
    long long b = (long long)i * 32;
    *(bf16x8*)&outp[b]      = h0;
    *(bf16x8*)&outp[b + 8]  = h1;
    *(bf16x8*)&outp[b + 16] = l0;
    *(bf16x8*)&outp[b + 24] = l1;
}

// ---------------- gather-mean (float4/thread) -> pair16 bf16 ----------------
__global__ __launch_bounds__(256) void aggmean_k(const float* __restrict__ feat,
                                                 const int* __restrict__ perm,
                                                 const int* __restrict__ offs,
                                                 short* __restrict__ mp, int N) {
    int tid = threadIdx.x;
    int node = blockIdx.x * 8 + (tid >> 5);
    int q = tid & 31;                       // channels q*4..q*4+3
    if (node >= N) return;
    int beg = offs[node], end = offs[node + 1];
    float ax = 0, ay = 0, az = 0, aw = 0;
    float bx = 0, by = 0, bz = 0, bw = 0;
    int i = beg;
    for (; i + 1 < end; i += 2) {
        float4 v0 = ((const float4*)feat)[(long long)perm[i] * 32 + q];
        float4 v1 = ((const float4*)feat)[(long long)perm[i + 1] * 32 + q];
        ax += v0.x; ay += v0.y; az += v0.z; aw += v0.w;
        bx += v1.x; by += v1.y; bz += v1.z; bw += v1.w;
    }
    if (i < end) {
        float4 v0 = ((const float4*)feat)[(long long)perm[i] * 32 + q];
        ax += v0.x; ay += v0.y; az += v0.z; aw += v0.w;
    }
    float rc = 1.0f / fmaxf((float)(end - beg), 1.0f);
    short2 c0 = cvt_split((ax + bx) * rc);
    short2 c1 = cvt_split((ay + by) * rc);
    short2 c2 = cvt_split((az + bz) * rc);
    short2 c3 = cvt_split((aw + bw) * rc);
    // pair16 layout: group = q>>2 (32 shorts), within = (q&3)*4
    long long base = (long long)node * 256 + (q >> 2) * 32 + (q & 3) * 4;
    *(short4*)&mp[base]      = make_short4(c0.x, c1.x, c2.x, c3.x);
    *(short4*)&mp[base + 16] = make_short4(c0.y, c1.y, c2.y, c3.y);
}

// ---------------- layer-2 agg fused epilogue: out = mean(g) + r2 + b2l ----------------
__global__ __launch_bounds__(256) void aggout_k(const float* __restrict__ g,
                                                const int* __restrict__ perm,
                                                const int* __restrict__ offs,
                                                const float* __restrict__ r2,
                                                const float* __restrict__ b2l,
                                                float* __restrict__ out, int N) {
    int tid = threadIdx.x;
    int node = blockIdx.x * 8 + (tid >> 5);
    int q = tid & 31;
    if (node >= N) return;
    int beg = offs[node], end = offs[node + 1];
    float ax = 0, ay = 0, az = 0, aw = 0;
    float bx = 0, by = 0, bz = 0, bw = 0;
    int i = beg;
    for (; i + 1 < end; i += 2) {
        float4 v0 = ((const float4*)g)[(long long)perm[i] * 32 + q];
        float4 v1 = ((const float4*)g)[(long long)perm[i + 1] * 32 + q];
        ax += v0.x; ay += v0.y; az += v0.z; aw += v0.w;
        bx += v1.x; by += v1.y; bz += v1.z; bw += v1.w;
    }
    if (i < end) {
        float4 v0 = ((const float4*)g)[(long long)perm[i] * 32 + q];
        ax += v0.x; ay += v0.y; az += v0.z; aw += v0.w;
    }
    float rc = 1.0f / fmaxf((float)(end - beg), 1.0f);
    float4 rv = ((const float4*)r2)[(long long)node * 32 + q];
    float4 bv = ((const float4*)b2l)[q];
    float4 o;
    o.x = (ax + bx) * rc + rv.x + bv.x;
    o.y = (ay + by) * rc + rv.y + bv.y;
    o.z = (az + bz) * rc + rv.z + bv.z;
    o.w = (aw + bw) * rc + rv.w + bv.w;
    ((float4*)out)[(long long)node * 32 + q] = o;
}

// ---------------- async global->LDS, 16B/lane ----------------
__device__ inline void gload16(const void* g, void* l) {
    __builtin_amdgcn_global_load_lds(
        (const __attribute__((address_space(1))) unsigned int*)g,
        (__attribute__((address_space(3))) unsigned int*)l,
        16, 0, 0);
}

// ================= split-bf16 MFMA GEMM, FULL-WIDTH 128x256 tile =================
// C ~= Ahi.Bhi + Ahi.Blo + Alo.Bhi. 782 blocks, 512 threads = 8 waves
// (2 row-halves x 4 col-quarters), 4x4 frags. K=256 in 8 stages BK=32.
// LAYER 1: A = mp/xp PAIR16 ([16 hi|16 lo] per 32-short group; chunks
//   hiC/hiC+2), B = W1 pair16. Epilogue writes h ELEMENT-INTERLEAVED
//   (uint = hi | lo<<16 per element) -> 64-B full-sector stores.
// LAYER 2: A = h interleaved (chunks 2lg/2lg+1, unpack hi/lo words in
//   VALU), B = W2 pair16. fp32 outputs g | r2.
// LDS = A 16 KiB + B 32 KiB = 48 KiB. Swizzle: chunk c of row r at slot
// c^(r&7); DMA pre-swizzles per-lane source chunk (k8s), single array/instr.
template <int LAYER>
__global__ __launch_bounds__(512, 4) void gemm_mfma_k(
        const short* __restrict__ Ap0, const short* __restrict__ Ap1,
        const short* __restrict__ Bp0, const short* __restrict__ Bp1,
        const float* __restrict__ bias,
        float* __restrict__ O0, float* __restrict__ O1,
        short* __restrict__ OP, int N) {
    __shared__ short As[128 * 64];   // 16 KiB
    __shared__ short Bs[256 * 64];   // 32 KiB

    const int m0 = blockIdx.x * 128;
    const int tid = threadIdx.x;
    const int lane = tid & 63;
    const int wid = tid >> 6;           // 0..7
    const int wm = wid >> 2, wn = wid & 3;
    const int lr = lane & 15, lg = lane >> 4;
    const int hiC = ((lg >> 1) << 2) | (lg & 1);   // pair16 hi chunk for k-chunk lg

    // DMA lane geometry: 8 rows x 8 slots x 16 B = 1 KB per issue
    const int r8 = lane >> 3;
    const int scs = lane & 7;
    const int k8s = scs ^ r8;          // pre-swizzled source chunk within 128 B slice

    f32x4 acc[4][4];
#pragma unroll
    for (int i = 0; i < 4; i++)
#pragma unroll
        for (int j = 0; j < 4; j++) acc[i][j] = (f32x4)0.0f;

#pragma unroll
    for (int kt = 0; kt < 8; ++kt) {
        __syncthreads();    // previous stage's readers done
        // ---- STAGE kt ----
        {
            const short* Asrc;
            int aoffk;
            if constexpr (LAYER == 1) { Asrc = (kt < 4) ? Ap0 : Ap1; aoffk = (kt & 3) * 64; }
            else                      { Asrc = Ap0;                  aoffk = kt * 64; }
#pragma unroll
            for (int it = 0; it < 2; ++it) {
                int seg = wid * 2 + it;          // 0..15
                int row = seg * 8 + r8;          // 0..127
                int gn = m0 + row;
                if (gn < N)
                    gload16(Asrc + (long long)gn * ((LAYER == 1) ? 256 : 512) + aoffk + k8s * 8,
                            &As[seg * 512]);
            }
#pragma unroll
            for (int it = 0; it < 4; ++it) {
                int seg = wid * 4 + it;          // 0..31
                int row = seg * 8 + r8;          // 0..255 (output col)
                const short* Bsrc;
                long long boff;
                if constexpr (LAYER == 1) {
                    Bsrc = (kt < 4) ? Bp0 : Bp1;             // W1l / W1r, rows 0..255
                    boff = (long long)row * 256 + (kt & 3) * 64;
                } else {
                    Bsrc = (row < 128) ? Bp0 : Bp1;          // W2l / W2r
                    boff = (long long)(row & 127) * 512 + kt * 64;
                }
                gload16(Bsrc + boff + k8s * 8, &Bs[seg * 512]);
            }
        }
        __syncthreads();    // drain DMA: stage kt ready

        // ---- COMPUTE: 1 k-step of 32 ----
        {
            bf16x8 bh[4], bl[4];
#pragma unroll
            for (int fc = 0; fc < 4; ++fc) {
                int c_ = wn * 64 + fc * 16 + lr;             // 0..255
                bh[fc] = *(const bf16x8*)&Bs[c_ * 64 + ((hiC    ) ^ (c_ & 7)) * 8];
                bl[fc] = *(const bf16x8*)&Bs[c_ * 64 + ((hiC + 2) ^ (c_ & 7)) * 8];
            }
#pragma unroll
            for (int fr = 0; fr < 4; ++fr) {
                int r_ = wm * 64 + fr * 16 + lr;             // 0..127
                bf16x8 ah, al;
                if constexpr (LAYER == 1) {
                    ah = *(const bf16x8*)&As[r_ * 64 + ((hiC    ) ^ (r_ & 7)) * 8];
                    al = *(const bf16x8*)&As[r_ * 64 + ((hiC + 2) ^ (r_ & 7)) * 8];
                } else {
                    // interleaved h: chunks 2lg (elems 8lg..+3), 2lg+1 (+4..+7)
                    u32x4 e0 = *(const u32x4*)&As[r_ * 64 + ((2 * lg    ) ^ (r_ & 7)) * 8];
                    u32x4 e1 = *(const u32x4*)&As[r_ * 64 + ((2 * lg + 1) ^ (r_ & 7)) * 8];
                    u32x4 hw, lw;
                    hw[0] = (e0[0] & 0xFFFFu) | (e0[1] << 16);
                    hw[1] = (e0[2] & 0xFFFFu) | (e0[3] << 16);
                    hw[2] = (e1[0] & 0xFFFFu) | (e1[1] << 16);
                    hw[3] = (e1[2] & 0xFFFFu) | (e1[3] << 16);
                    lw[0] = (e0[0] >> 16) | (e0[1] & 0xFFFF0000u);
                    lw[1] = (e0[2] >> 16) | (e0[3] & 0xFFFF0000u);
                    lw[2] = (e1[0] >> 16) | (e1[1] & 0xFFFF0000u);
                    lw[3] = (e1[2] >> 16) | (e1[3] & 0xFFFF0000u);
                    ah = __builtin_bit_cast(bf16x8, hw);
                    al = __builtin_bit_cast(bf16x8, lw);
                }
#pragma unroll
                for (int fc = 0; fc < 4; ++fc) {
                    acc[fr][fc] = __builtin_amdgcn_mfma_f32_16x16x32_bf16(al, bh[fc], acc[fr][fc], 0, 0, 0);
                    acc[fr][fc] = __builtin_amdgcn_mfma_f32_16x16x32_bf16(ah, bl[fc], acc[fr][fc], 0, 0, 0);
                    acc[fr][fc] = __builtin_amdgcn_mfma_f32_16x16x32_bf16(ah, bh[fc], acc[fr][fc], 0, 0, 0);
                }
            }
        }
    }

    // ---- epilogue: C/D map col=lane&15, row=(lane>>4)*4+reg ----
    if constexpr (LAYER == 1) {
        // write h ELEMENT-INTERLEAVED: uint = hi | lo<<16, row stride 256 uints
        unsigned* OPu = (unsigned*)OP;
#pragma unroll
        for (int fc = 0; fc < 4; ++fc) {
            int col = wn * 64 + fc * 16 + lr;       // 0..255
            float bv = bias[col];
#pragma unroll
            for (int fr = 0; fr < 4; ++fr) {
#pragma unroll
                for (int j = 0; j < 4; ++j) {
                    int row = m0 + wm * 64 + fr * 16 + lg * 4 + j;
                    if (row < N) {
                        float val = fmaxf(acc[fr][fc][j] + bv, 0.0f);
                        short2 cc = cvt_split(val);
                        OPu[(long long)row * 256 + col] =
                            (unsigned)(unsigned short)cc.x |
                            ((unsigned)(unsigned short)cc.y << 16);
                    }
                }
            }
        }
    } else {
#pragma unroll
        for (int fc = 0; fc < 4; ++fc) {
            int col = wn * 64 + fc * 16 + lr;       // 0..255
            float* dp = (col < 128) ? O0 : O1;      // uniform per wn
            int dcol = col & 127;
#pragma unroll
            for (int fr = 0; fr < 4; ++fr) {
#pragma unroll
                for (int j = 0; j < 4; ++j) {
                    int row = m0 + wm * 64 + fr * 16 + lg * 4 + j;
                    if (row < N)
                        dp[(long long)row * 128 + dcol] = acc[fr][fc][j];
                }
            }
        }
    }
}

extern "C" void kernel_launch(void* const* d_in, const int* in_sizes, int n_in,
                              void* d_out, int out_size, void* d_ws, size_t ws_size,
                              hipStream_t stream) {
    const float* x   = (const float*)d_in[0];
    const int*   ei  = (const int*)d_in[1];     // [2, E]
    const float* W1l = (const float*)d_in[2];
    const float* b1l = (const float*)d_in[3];
    const float* W1r = (const float*)d_in[4];
    const float* W2l = (const float*)d_in[5];
    const float* b2l = (const float*)d_in[6];
    const float* W2r = (const float*)d_in[7];
    float* out = (float*)d_out;

    const int N = N_NODES, E = N_EDGES;
    const int* srcI = ei;
    const int* dstI = ei + E;

    char* ws = (char*)d_ws;
    size_t off = 0;
    auto alloc = [&](size_t bytes) {
        size_t o = off;
        off += (bytes + 511) & ~(size_t)511;
        return o;
    };
    size_t off_cnt   = alloc((size_t)N * 4);
    size_t off_offs  = alloc((size_t)(N + 1) * 4);
    size_t off_cur   = alloc((size_t)N * 4);
    size_t off_bsum  = alloc((size_t)SCAN_NB * 4);
    size_t off_boff  = alloc((size_t)SCAN_NB * 4);
    size_t off_perm  = alloc((size_t)E * 4);
    size_t off_xp    = alloc((size_t)N * 256 * 2);     // x pair16
    size_t off_mp    = alloc((size_t)N * 256 * 2);     // mean pair16; reused as g (fp32)
    size_t off_hp    = alloc((size_t)N * 512 * 2);     // h element-interleaved
    size_t off_r2    = alloc((size_t)N * 128 * 4);     // fp32
    size_t off_w     = alloc((size_t)4 * 65536 * 2);   // 4 paired weights
    int*   cntI  = (int*)(ws + off_cnt);
    int*   offs  = (int*)(ws + off_offs);
    int*   cur   = (int*)(ws + off_cur);
    int*   bsum  = (int*)(ws + off_bsum);
    int*   boff  = (int*)(ws + off_boff);
    int*   perm  = (int*)(ws + off_perm);
    short* xp    = (short*)(ws + off_xp);
    short* mp    = (short*)(ws + off_mp);
    float* g     = (float*)(ws + off_mp);              // aliases mean (dead after gemm1)
    short* hp    = (short*)(ws + off_hp);
    float* r2    = (float*)(ws + off_r2);
    short* wbuf  = (short*)(ws + off_w);
    const int WSZ = 65536;                             // 256*128 elems paired
    short* w1lp = wbuf;            short* w1rp = wbuf + WSZ;
    short* w2lp = wbuf + 2 * WSZ;  short* w2rp = wbuf + 3 * WSZ;

    // ---- CSR build ----
    (void)hipMemsetAsync(cntI, 0, (size_t)N * 4, stream);
    count_int_k<<<(E + 255) / 256, 256, 0, stream>>>(dstI, cntI, E);
    scan1_k<<<SCAN_NB, 256, 0, stream>>>(cntI, offs, bsum, N);
    scan2_k<<<1, 256, 0, stream>>>(bsum, boff, SCAN_NB);
    scan3_k<<<(N + 255) / 256, 256, 0, stream>>>(offs, cur, boff, N, E);
    fill_k<<<(E + 255) / 256, 256, 0, stream>>>(srcI, dstI, cur, perm, E);

    // ---- pair16 conversions ----
    {
        int n16x = N * 8;                          // N*128/16
        cvt_pair_k<<<(n16x + 255) / 256, 256, 0, stream>>>(x, xp, n16x);
        int n16w = 256 * 128 / 16;                 // 2048
        cvt_pair_k<<<(n16w + 255) / 256, 256, 0, stream>>>(W1l, w1lp, n16w);
        cvt_pair_k<<<(n16w + 255) / 256, 256, 0, stream>>>(W1r, w1rp, n16w);
        cvt_pair_k<<<(n16w + 255) / 256, 256, 0, stream>>>(W2l, w2lp, n16w);
        cvt_pair_k<<<(n16w + 255) / 256, 256, 0, stream>>>(W2r, w2rp, n16w);
    }

    // ---- layer 1 ----
    aggmean_k<<<(N + 7) / 8, 256, 0, stream>>>(x, perm, offs, mp, N);
    {
        int nblk = (N + 127) / 128;
        gemm_mfma_k<1><<<nblk, 512, 0, stream>>>(mp, xp, w1lp, w1rp,
                                                 b1l, nullptr, nullptr, hp, N);
    }

    // ---- layer 2 ----
    {
        int nblk = (N + 127) / 128;
        gemm_mfma_k<2><<<nblk, 512, 0, stream>>>(hp, hp, w2lp, w2rp,
                                                 nullptr, g, r2, nullptr, N);
    }
    aggout_k<<<(N + 7) / 8, 256, 0, stream>>>(g, perm, offs, r2, b2l, out, N);
}

// Round 17
// 335.399 us; speedup vs baseline: 1.4988x; 1.3551x over previous
//
#include <hip/hip_runtime.h>

#define N_NODES 100000
#define N_EDGES 800000
// IN=128, HID=256, OUT=128
#define SCAN_CHUNK 1024
#define SCAN_NB ((N_NODES + SCAN_CHUNK - 1) / SCAN_CHUNK)   // 98

typedef __attribute__((ext_vector_type(8))) _Float16 f16x8;
typedef __attribute__((ext_vector_type(4))) float f32x4;

// ---------------- degree count (int atomics) ----------------
__global__ void count_int_k(const int* __restrict__ dst, int* __restrict__ cnt, int E) {
    int i = blockIdx.x * blockDim.x + threadIdx.x;
    if (i < E) atomicAdd(&cnt[dst[i]], 1);
}

// ---------------- scan pass 1 ----------------
__global__ __launch_bounds__(256) void scan1_k(const int* __restrict__ cnt,
                                               int* __restrict__ offs,
                                               int* __restrict__ bsums, int N) {
    __shared__ int s[256];
    int t = threadIdx.x;
    int base = blockIdx.x * SCAN_CHUNK + t * 4;
    int v0 = (base + 0 < N) ? cnt[base + 0] : 0;
    int v1 = (base + 1 < N) ? cnt[base + 1] : 0;
    int v2 = (base + 2 < N) ? cnt[base + 2] : 0;
    int v3 = (base + 3 < N) ? cnt[base + 3] : 0;
    int tsum = v0 + v1 + v2 + v3;
    s[t] = tsum;
    __syncthreads();
    for (int off = 1; off < 256; off <<= 1) {
        int val = (t >= off) ? s[t - off] : 0;
        __syncthreads();
        s[t] += val;
        __syncthreads();
    }
    int excl = s[t] - tsum;
    if (base + 0 < N) offs[base + 0] = excl;
    if (base + 1 < N) offs[base + 1] = excl + v0;
    if (base + 2 < N) offs[base + 2] = excl + v0 + v1;
    if (base + 3 < N) offs[base + 3] = excl + v0 + v1 + v2;
    if (t == 255) bsums[blockIdx.x] = s[255];
}

// ---------------- scan pass 2 ----------------
__global__ __launch_bounds__(256) void scan2_k(const int* __restrict__ bsums,
                                               int* __restrict__ boffs, int nb) {
    __shared__ int s[256];
    int t = threadIdx.x;
    int v = (t < nb) ? bsums[t] : 0;
    s[t] = v;
    __syncthreads();
    for (int off = 1; off < 256; off <<= 1) {
        int val = (t >= off) ? s[t - off] : 0;
        __syncthreads();
        s[t] += val;
        __syncthreads();
    }
    if (t < nb) boffs[t] = s[t] - v;
}

// ---------------- scan pass 3 ----------------
__global__ void scan3_k(int* __restrict__ offs, int* __restrict__ cursor,
                        const int* __restrict__ boffs, int N, int E) {
    int i = blockIdx.x * blockDim.x + threadIdx.x;
    if (i < N) {
        int v = offs[i] + boffs[i >> 10];
        offs[i] = v;
        cursor[i] = v;
    }
    if (i == 0) offs[N] = E;
}

// ---------------- bucket fill ----------------
__global__ void fill_k(const int* __restrict__ src, const int* __restrict__ dst,
                       int* __restrict__ cursor, int* __restrict__ perm, int E) {
    int e = blockIdx.x * blockDim.x + threadIdx.x;
    if (e < E) {
        int d = dst[e];
        int slot = atomicAdd(&cursor[d], 1);
        perm[slot] = src[e];
    }
}

// ---------------- bulk f32 -> f16 conversion (8 floats/thread) ----------------
__global__ __launch_bounds__(256) void cvt_f16_k(const float* __restrict__ in,
                                                 _Float16* __restrict__ outp, int n8) {
    int i = blockIdx.x * blockDim.x + threadIdx.x;
    if (i >= n8) return;
    const float4* p = (const float4*)in + (long long)i * 2;
    float4 v0 = p[0], v1 = p[1];
    f16x8 h;
    h[0] = (_Float16)v0.x; h[1] = (_Float16)v0.y;
    h[2] = (_Float16)v0.z; h[3] = (_Float16)v0.w;
    h[4] = (_Float16)v1.x; h[5] = (_Float16)v1.y;
    h[6] = (_Float16)v1.z; h[7] = (_Float16)v1.w;
    *(f16x8*)&outp[(long long)i * 8] = h;
}

// ---------------- gather-mean (float4/thread) -> f16 ----------------
__global__ __launch_bounds__(256) void aggmean_k(const float* __restrict__ feat,
                                                 const int* __restrict__ perm,
                                                 const int* __restrict__ offs,
                                                 _Float16* __restrict__ m16, int N) {
    int tid = threadIdx.x;
    int node = blockIdx.x * 8 + (tid >> 5);
    int q = tid & 31;                       // channels q*4..q*4+3
    if (node >= N) return;
    int beg = offs[node], end = offs[node + 1];
    float ax = 0, ay = 0, az = 0, aw = 0;
    float bx = 0, by = 0, bz = 0, bw = 0;
    int i = beg;
    for (; i + 1 < end; i += 2) {
        float4 v0 = ((const float4*)feat)[(long long)perm[i] * 32 + q];
        float4 v1 = ((const float4*)feat)[(long long)perm[i + 1] * 32 + q];
        ax += v0.x; ay += v0.y; az += v0.z; aw += v0.w;
        bx += v1.x; by += v1.y; bz += v1.z; bw += v1.w;
    }
    if (i < end) {
        float4 v0 = ((const float4*)feat)[(long long)perm[i] * 32 + q];
        ax += v0.x; ay += v0.y; az += v0.z; aw += v0.w;
    }
    float rc = 1.0f / fmaxf((float)(end - beg), 1.0f);
    _Float16 h0 = (_Float16)((ax + bx) * rc);
    _Float16 h1 = (_Float16)((ay + by) * rc);
    _Float16 h2 = (_Float16)((az + bz) * rc);
    _Float16 h3 = (_Float16)((aw + bw) * rc);
    typedef __attribute__((ext_vector_type(4))) _Float16 f16x4;
    f16x4 v; v[0] = h0; v[1] = h1; v[2] = h2; v[3] = h3;
    *(f16x4*)&m16[(long long)node * 128 + q * 4] = v;
}

// ---------------- layer-2 agg fused epilogue: out = mean(g) + r2 + b2l ----------------
__global__ __launch_bounds__(256) void aggout_k(const float* __restrict__ g,
                                                const int* __restrict__ perm,
                                                const int* __restrict__ offs,
                                                const float* __restrict__ r2,
                                                const float* __restrict__ b2l,
                                                float* __restrict__ out, int N) {
    int tid = threadIdx.x;
    int node = blockIdx.x * 8 + (tid >> 5);
    int q = tid & 31;
    if (node >= N) return;
    int beg = offs[node], end = offs[node + 1];
    float ax = 0, ay = 0, az = 0, aw = 0;
    float bx = 0, by = 0, bz = 0, bw = 0;
    int i = beg;
    for (; i + 1 < end; i += 2) {
        float4 v0 = ((const float4*)g)[(long long)perm[i] * 32 + q];
        float4 v1 = ((const float4*)g)[(long long)perm[i + 1] * 32 + q];
        ax += v0.x; ay += v0.y; az += v0.z; aw += v0.w;
        bx += v1.x; by += v1.y; bz += v1.z; bw += v1.w;
    }
    if (i < end) {
        float4 v0 = ((const float4*)g)[(long long)perm[i] * 32 + q];
        ax += v0.x; ay += v0.y; az += v0.z; aw += v0.w;
    }
    float rc = 1.0f / fmaxf((float)(end - beg), 1.0f);
    float4 rv = ((const float4*)r2)[(long long)node * 32 + q];
    float4 bv = ((const float4*)b2l)[q];
    float4 o;
    o.x = (ax + bx) * rc + rv.x + bv.x;
    o.y = (ay + by) * rc + rv.y + bv.y;
    o.z = (az + bz) * rc + rv.z + bv.z;
    o.w = (aw + bw) * rc + rv.w + bv.w;
    ((float4*)out)[(long long)node * 32 + q] = o;
}

// ---------------- async global->LDS, 16B/lane ----------------
__device__ inline void gload16(const void* g, void* l) {
    __builtin_amdgcn_global_load_lds(
        (const __attribute__((address_space(1))) unsigned int*)g,
        (__attribute__((address_space(3))) unsigned int*)l,
        16, 0, 0);
}

// ================= fp16 MFMA GEMM, FULL-WIDTH 128x256 tile, BK=64, 4 stages ==========
// C = A @ B^T in fp16 (single term; fp32 accumulate). 782 blocks, 512 threads
// = 8 waves (2 row-halves x 4 col-quarters), 4x4 16x16x32_f16 frags.
// K=256 in 4 stages of BK=64. Row stage-slice = 64 halfs = 128 B = 8 chunks of
// 16 B; k-step ks (0/1) + k-chunk lg -> chunk c = ks*4+lg. LDS = A 16 KiB +
// B 32 KiB = 48 KiB (3 blocks/CU). Swizzle: chunk c of row r at slot c^(r&7);
// DMA pre-swizzles the per-lane source chunk (k8s), single array per instr.
// LAYER 1: A k-halves = m16/x16 (stride 128), B k-halves = W1l/W1r (stride 128),
//   epilogue relu+bias -> h f16 (stride 256).
// LAYER 2: A = h16 (stride 256), B row<128 -> W2l else W2r (stride 256),
//   fp32 outputs g | r2.
template <int LAYER>
__global__ __launch_bounds__(512, 4) void gemm_mfma_k(
        const _Float16* __restrict__ Ap0, const _Float16* __restrict__ Ap1,
        const _Float16* __restrict__ Bp0, const _Float16* __restrict__ Bp1,
        const float* __restrict__ bias,
        float* __restrict__ O0, float* __restrict__ O1,
        _Float16* __restrict__ OH, int N) {
    constexpr int RSA = (LAYER == 1) ? 128 : 256;   // A row stride (halfs)
    __shared__ _Float16 As[128 * 64];   // 16 KiB
    __shared__ _Float16 Bs[256 * 64];   // 32 KiB

    const int m0 = blockIdx.x * 128;
    const int tid = threadIdx.x;
    const int lane = tid & 63;
    const int wid = tid >> 6;           // 0..7
    const int wm = wid >> 2, wn = wid & 3;
    const int lr = lane & 15, lg = lane >> 4;

    // DMA lane geometry: 8 rows x 8 slots x 16 B = 1 KB per issue
    const int r8 = lane >> 3;
    const int scs = lane & 7;
    const int k8s = scs ^ r8;          // pre-swizzled source chunk within 128 B slice

    f32x4 acc[4][4];
#pragma unroll
    for (int i = 0; i < 4; i++)
#pragma unroll
        for (int j = 0; j < 4; j++) acc[i][j] = (f32x4)0.0f;

#pragma unroll
    for (int kt = 0; kt < 4; ++kt) {
        __syncthreads();    // previous stage's readers done
        // ---- STAGE kt: A 16 segs (2/wave), B 32 segs (4/wave) ----
        {
            const _Float16* Asrc;
            int aoffk;
            if constexpr (LAYER == 1) { Asrc = (kt < 2) ? Ap0 : Ap1; aoffk = (kt & 1) * 64; }
            else                      { Asrc = Ap0;                  aoffk = kt * 64; }
#pragma unroll
            for (int it = 0; it < 2; ++it) {
                int seg = wid * 2 + it;          // 0..15
                int row = seg * 8 + r8;          // 0..127
                int gn = m0 + row;
                if (gn < N)
                    gload16(Asrc + (long long)gn * RSA + aoffk + k8s * 8, &As[seg * 512]);
            }
#pragma unroll
            for (int it = 0; it < 4; ++it) {
                int seg = wid * 4 + it;          // 0..31
                int row = seg * 8 + r8;          // 0..255 (output col)
                const _Float16* Bsrc;
                long long boff;
                if constexpr (LAYER == 1) {
                    Bsrc = (kt < 2) ? Bp0 : Bp1;             // W1l / W1r, rows 0..255
                    boff = (long long)row * 128 + (kt & 1) * 64;
                } else {
                    Bsrc = (row < 128) ? Bp0 : Bp1;          // W2l / W2r
                    boff = (long long)(row & 127) * 256 + kt * 64;
                }
                gload16(Bsrc + boff + k8s * 8, &Bs[seg * 512]);
            }
        }
        __syncthreads();    // drain DMA: stage kt ready

        // ---- COMPUTE: 2 k-steps of 32 ----
#pragma unroll
        for (int ks = 0; ks < 2; ++ks) {
            const int c = ks * 4 + lg;           // k-chunk 0..7
            f16x8 bf[4];
#pragma unroll
            for (int fc = 0; fc < 4; ++fc) {
                int c_ = wn * 64 + fc * 16 + lr;             // 0..255
                bf[fc] = *(const f16x8*)&Bs[c_ * 64 + (c ^ (c_ & 7)) * 8];
            }
#pragma unroll
            for (int fr = 0; fr < 4; ++fr) {
                int r_ = wm * 64 + fr * 16 + lr;             // 0..127
                f16x8 af = *(const f16x8*)&As[r_ * 64 + (c ^ (r_ & 7)) * 8];
#pragma unroll
                for (int fc = 0; fc < 4; ++fc)
                    acc[fr][fc] = __builtin_amdgcn_mfma_f32_16x16x32_f16(af, bf[fc], acc[fr][fc], 0, 0, 0);
            }
        }
    }

    // ---- epilogue: C/D map col=lane&15, row=(lane>>4)*4+reg ----
    if constexpr (LAYER == 1) {
#pragma unroll
        for (int fc = 0; fc < 4; ++fc) {
            int col = wn * 64 + fc * 16 + lr;       // 0..255
            float bv = bias[col];
#pragma unroll
            for (int fr = 0; fr < 4; ++fr) {
#pragma unroll
                for (int j = 0; j < 4; ++j) {
                    int row = m0 + wm * 64 + fr * 16 + lg * 4 + j;
                    if (row < N)
                        OH[(long long)row * 256 + col] =
                            (_Float16)fmaxf(acc[fr][fc][j] + bv, 0.0f);
                }
            }
        }
    } else {
#pragma unroll
        for (int fc = 0; fc < 4; ++fc) {
            int col = wn * 64 + fc * 16 + lr;       // 0..255
            float* dp = (col < 128) ? O0 : O1;      // uniform per wn
            int dcol = col & 127;
#pragma unroll
            for (int fr = 0; fr < 4; ++fr) {
#pragma unroll
                for (int j = 0; j < 4; ++j) {
                    int row = m0 + wm * 64 + fr * 16 + lg * 4 + j;
                    if (row < N)
                        dp[(long long)row * 128 + dcol] = acc[fr][fc][j];
                }
            }
        }
    }
}

extern "C" void kernel_launch(void* const* d_in, const int* in_sizes, int n_in,
                              void* d_out, int out_size, void* d_ws, size_t ws_size,
                              hipStream_t stream) {
    const float* x   = (const float*)d_in[0];
    const int*   ei  = (const int*)d_in[1];     // [2, E]
    const float* W1l = (const float*)d_in[2];
    const float* b1l = (const float*)d_in[3];
    const float* W1r = (const float*)d_in[4];
    const float* W2l = (const float*)d_in[5];
    const float* b2l = (const float*)d_in[6];
    const float* W2r = (const float*)d_in[7];
    float* out = (float*)d_out;

    const int N = N_NODES, E = N_EDGES;
    const int* srcI = ei;
    const int* dstI = ei + E;

    char* ws = (char*)d_ws;
    size_t off = 0;
    auto alloc = [&](size_t bytes) {
        size_t o = off;
        off += (bytes + 511) & ~(size_t)511;
        return o;
    };
    size_t off_cnt   = alloc((size_t)N * 4);
    size_t off_offs  = alloc((size_t)(N + 1) * 4);
    size_t off_cur   = alloc((size_t)N * 4);
    size_t off_bsum  = alloc((size_t)SCAN_NB * 4);
    size_t off_boff  = alloc((size_t)SCAN_NB * 4);
    size_t off_perm  = alloc((size_t)E * 4);
    size_t off_x16   = alloc((size_t)N * 128 * 2);     // x f16
    size_t off_m16   = alloc((size_t)N * 128 * 2);     // mean f16
    size_t off_h16   = alloc((size_t)N * 256 * 2);     // h f16
    size_t off_g     = alloc((size_t)N * 128 * 4);     // fp32
    size_t off_r2    = alloc((size_t)N * 128 * 4);     // fp32
    size_t off_w     = alloc((size_t)4 * 32768 * 2);   // 4 f16 weights, 64 KB each
    int*      cntI = (int*)(ws + off_cnt);
    int*      offs = (int*)(ws + off_offs);
    int*      cur  = (int*)(ws + off_cur);
    int*      bsum = (int*)(ws + off_bsum);
    int*      boff = (int*)(ws + off_boff);
    int*      perm = (int*)(ws + off_perm);
    _Float16* x16  = (_Float16*)(ws + off_x16);
    _Float16* m16  = (_Float16*)(ws + off_m16);
    _Float16* h16  = (_Float16*)(ws + off_h16);
    float*    g    = (float*)(ws + off_g);
    float*    r2   = (float*)(ws + off_r2);
    _Float16* wbuf = (_Float16*)(ws + off_w);
    const int WSZ = 32768;                             // 256*128 elems
    _Float16* w1l16 = wbuf;            _Float16* w1r16 = wbuf + WSZ;
    _Float16* w2l16 = wbuf + 2 * WSZ;  _Float16* w2r16 = wbuf + 3 * WSZ;

    // ---- CSR build ----
    (void)hipMemsetAsync(cntI, 0, (size_t)N * 4, stream);
    count_int_k<<<(E + 255) / 256, 256, 0, stream>>>(dstI, cntI, E);
    scan1_k<<<SCAN_NB, 256, 0, stream>>>(cntI, offs, bsum, N);
    scan2_k<<<1, 256, 0, stream>>>(bsum, boff, SCAN_NB);
    scan3_k<<<(N + 255) / 256, 256, 0, stream>>>(offs, cur, boff, N, E);
    fill_k<<<(E + 255) / 256, 256, 0, stream>>>(srcI, dstI, cur, perm, E);

    // ---- f16 conversions ----
    {
        int n8x = N * 16;                          // N*128/8
        cvt_f16_k<<<(n8x + 255) / 256, 256, 0, stream>>>(x, x16, n8x);
        int n8w = 32768 / 8;                       // 4096
        cvt_f16_k<<<(n8w + 255) / 256, 256, 0, stream>>>(W1l, w1l16, n8w);
        cvt_f16_k<<<(n8w + 255) / 256, 256, 0, stream>>>(W1r, w1r16, n8w);
        cvt_f16_k<<<(n8w + 255) / 256, 256, 0, stream>>>(W2l, w2l16, n8w);
        cvt_f16_k<<<(n8w + 255) / 256, 256, 0, stream>>>(W2r, w2r16, n8w);
    }

    // ---- layer 1 ----
    aggmean_k<<<(N + 7) / 8, 256, 0, stream>>>(x, perm, offs, m16, N);
    {
        int nblk = (N + 127) / 128;
        gemm_mfma_k<1><<<nblk, 512, 0, stream>>>(m16, x16, w1l16, w1r16,
                                                 b1l, nullptr, nullptr, h16, N);
    }

    // ---- layer 2 ----
    {
        int nblk = (N + 127) / 128;
        gemm_mfma_k<2><<<nblk, 512, 0, stream>>>(h16, h16, w2l16, w2r16,
                                                 nullptr, g, r2, nullptr, N);
    }
    aggout_k<<<(N + 7) / 8, 256, 0, stream>>>(g, perm, offs, r2, b2l, out, N);
}

// Round 18
// 297.213 us; speedup vs baseline: 1.6914x; 1.1285x over previous
//
#include <hip/hip_runtime.h>

#define N_NODES 100000
#define N_EDGES 800000
// IN=128, HID=256, OUT=128
#define SCAN_CHUNK 1024
#define SCAN_NB ((N_NODES + SCAN_CHUNK - 1) / SCAN_CHUNK)   // 98

typedef __attribute__((ext_vector_type(8))) _Float16 f16x8;
typedef __attribute__((ext_vector_type(4))) _Float16 f16x4;
typedef __attribute__((ext_vector_type(4))) float f32x4;

// ---------------- degree count (int atomics) ----------------
__global__ void count_int_k(const int* __restrict__ dst, int* __restrict__ cnt, int E) {
    int i = blockIdx.x * blockDim.x + threadIdx.x;
    if (i < E) atomicAdd(&cnt[dst[i]], 1);
}

// ---------------- scan pass 1 ----------------
__global__ __launch_bounds__(256) void scan1_k(const int* __restrict__ cnt,
                                               int* __restrict__ offs,
                                               int* __restrict__ bsums, int N) {
    __shared__ int s[256];
    int t = threadIdx.x;
    int base = blockIdx.x * SCAN_CHUNK + t * 4;
    int v0 = (base + 0 < N) ? cnt[base + 0] : 0;
    int v1 = (base + 1 < N) ? cnt[base + 1] : 0;
    int v2 = (base + 2 < N) ? cnt[base + 2] : 0;
    int v3 = (base + 3 < N) ? cnt[base + 3] : 0;
    int tsum = v0 + v1 + v2 + v3;
    s[t] = tsum;
    __syncthreads();
    for (int off = 1; off < 256; off <<= 1) {
        int val = (t >= off) ? s[t - off] : 0;
        __syncthreads();
        s[t] += val;
        __syncthreads();
    }
    int excl = s[t] - tsum;
    if (base + 0 < N) offs[base + 0] = excl;
    if (base + 1 < N) offs[base + 1] = excl + v0;
    if (base + 2 < N) offs[base + 2] = excl + v0 + v1;
    if (base + 3 < N) offs[base + 3] = excl + v0 + v1 + v2;
    if (t == 255) bsums[blockIdx.x] = s[255];
}

// ---------------- scan pass 2 ----------------
__global__ __launch_bounds__(256) void scan2_k(const int* __restrict__ bsums,
                                               int* __restrict__ boffs, int nb) {
    __shared__ int s[256];
    int t = threadIdx.x;
    int v = (t < nb) ? bsums[t] : 0;
    s[t] = v;
    __syncthreads();
    for (int off = 1; off < 256; off <<= 1) {
        int val = (t >= off) ? s[t - off] : 0;
        __syncthreads();
        s[t] += val;
        __syncthreads();
    }
    if (t < nb) boffs[t] = s[t] - v;
}

// ---------------- scan pass 3 ----------------
__global__ void scan3_k(int* __restrict__ offs, int* __restrict__ cursor,
                        const int* __restrict__ boffs, int N, int E) {
    int i = blockIdx.x * blockDim.x + threadIdx.x;
    if (i < N) {
        int v = offs[i] + boffs[i >> 10];
        offs[i] = v;
        cursor[i] = v;
    }
    if (i == 0) offs[N] = E;
}

// ---------------- bucket fill ----------------
__global__ void fill_k(const int* __restrict__ src, const int* __restrict__ dst,
                       int* __restrict__ cursor, int* __restrict__ perm, int E) {
    int e = blockIdx.x * blockDim.x + threadIdx.x;
    if (e < E) {
        int d = dst[e];
        int slot = atomicAdd(&cursor[d], 1);
        perm[slot] = src[e];
    }
}

// ---------------- bulk f32 -> f16 conversion (8 floats/thread) ----------------
__global__ __launch_bounds__(256) void cvt_f16_k(const float* __restrict__ in,
                                                 _Float16* __restrict__ outp, int n8) {
    int i = blockIdx.x * blockDim.x + threadIdx.x;
    if (i >= n8) return;
    const float4* p = (const float4*)in + (long long)i * 2;
    float4 v0 = p[0], v1 = p[1];
    f16x8 h;
    h[0] = (_Float16)v0.x; h[1] = (_Float16)v0.y;
    h[2] = (_Float16)v0.z; h[3] = (_Float16)v0.w;
    h[4] = (_Float16)v1.x; h[5] = (_Float16)v1.y;
    h[6] = (_Float16)v1.z; h[7] = (_Float16)v1.w;
    *(f16x8*)&outp[(long long)i * 8] = h;
}

// ---------------- gather-mean over f16 rows (f16x4/thread) -> f16 ----------------
__global__ __launch_bounds__(256) void aggmean_k(const _Float16* __restrict__ feat16,
                                                 const int* __restrict__ perm,
                                                 const int* __restrict__ offs,
                                                 _Float16* __restrict__ m16, int N) {
    int tid = threadIdx.x;
    int node = blockIdx.x * 8 + (tid >> 5);
    int q = tid & 31;                       // channels q*4..q*4+3
    if (node >= N) return;
    int beg = offs[node], end = offs[node + 1];
    float ax = 0, ay = 0, az = 0, aw = 0;
    float bx = 0, by = 0, bz = 0, bw = 0;
    int i = beg;
    for (; i + 1 < end; i += 2) {
        f16x4 v0 = *(const f16x4*)&feat16[(long long)perm[i] * 128 + q * 4];
        f16x4 v1 = *(const f16x4*)&feat16[(long long)perm[i + 1] * 128 + q * 4];
        ax += (float)v0[0]; ay += (float)v0[1]; az += (float)v0[2]; aw += (float)v0[3];
        bx += (float)v1[0]; by += (float)v1[1]; bz += (float)v1[2]; bw += (float)v1[3];
    }
    if (i < end) {
        f16x4 v0 = *(const f16x4*)&feat16[(long long)perm[i] * 128 + q * 4];
        ax += (float)v0[0]; ay += (float)v0[1]; az += (float)v0[2]; aw += (float)v0[3];
    }
    float rc = 1.0f / fmaxf((float)(end - beg), 1.0f);
    f16x4 v;
    v[0] = (_Float16)((ax + bx) * rc);
    v[1] = (_Float16)((ay + by) * rc);
    v[2] = (_Float16)((az + bz) * rc);
    v[3] = (_Float16)((aw + bw) * rc);
    *(f16x4*)&m16[(long long)node * 128 + q * 4] = v;
}

// ---------------- layer-2 agg fused epilogue: out = mean(g16) + r2 + b2l ----------------
__global__ __launch_bounds__(256) void aggout_k(const _Float16* __restrict__ g16,
                                                const int* __restrict__ perm,
                                                const int* __restrict__ offs,
                                                const float* __restrict__ r2,
                                                const float* __restrict__ b2l,
                                                float* __restrict__ out, int N) {
    int tid = threadIdx.x;
    int node = blockIdx.x * 8 + (tid >> 5);
    int q = tid & 31;
    if (node >= N) return;
    int beg = offs[node], end = offs[node + 1];
    float ax = 0, ay = 0, az = 0, aw = 0;
    float bx = 0, by = 0, bz = 0, bw = 0;
    int i = beg;
    for (; i + 1 < end; i += 2) {
        f16x4 v0 = *(const f16x4*)&g16[(long long)perm[i] * 128 + q * 4];
        f16x4 v1 = *(const f16x4*)&g16[(long long)perm[i + 1] * 128 + q * 4];
        ax += (float)v0[0]; ay += (float)v0[1]; az += (float)v0[2]; aw += (float)v0[3];
        bx += (float)v1[0]; by += (float)v1[1]; bz += (float)v1[2]; bw += (float)v1[3];
    }
    if (i < end) {
        f16x4 v0 = *(const f16x4*)&g16[(long long)perm[i] * 128 + q * 4];
        ax += (float)v0[0]; ay += (float)v0[1]; az += (float)v0[2]; aw += (float)v0[3];
    }
    float rc = 1.0f / fmaxf((float)(end - beg), 1.0f);
    float4 rv = ((const float4*)r2)[(long long)node * 32 + q];
    float4 bv = ((const float4*)b2l)[q];
    float4 o;
    o.x = (ax + bx) * rc + rv.x + bv.x;
    o.y = (ay + by) * rc + rv.y + bv.y;
    o.z = (az + bz) * rc + rv.z + bv.z;
    o.w = (aw + bw) * rc + rv.w + bv.w;
    ((float4*)out)[(long long)node * 32 + q] = o;
}

// ---------------- async global->LDS, 16B/lane ----------------
__device__ inline void gload16(const void* g, void* l) {
    __builtin_amdgcn_global_load_lds(
        (const __attribute__((address_space(1))) unsigned int*)g,
        (__attribute__((address_space(3))) unsigned int*)l,
        16, 0, 0);
}

// ================= fp16 MFMA GEMM, FULL-WIDTH 128x256 tile, BK=64, 4 stages ==========
// C = A @ B^T in fp16 (fp32 accumulate). 782 blocks, 512 threads = 8 waves
// (2 row-halves x 4 col-quarters), 4x4 16x16x32_f16 frags. K=256 in 4 stages
// of BK=64. LDS = A 16 KiB + B 32 KiB = 48 KiB. Swizzle: chunk c of row r at
// slot c^(r&7); DMA pre-swizzles the per-lane source chunk (k8s).
// LAYER 1: A k-halves = m16/x16 (stride 128), B k-halves = W1l/W1r (128),
//   epilogue relu+bias -> h f16 (stride 256) via OH.
// LAYER 2: A = h16 (stride 256), B row<128 -> W2l else W2r (stride 256),
//   outputs g f16 (via OH, cols 0..127) | r2 fp32 (via O1, cols 128..255).
template <int LAYER>
__global__ __launch_bounds__(512, 4) void gemm_mfma_k(
        const _Float16* __restrict__ Ap0, const _Float16* __restrict__ Ap1,
        const _Float16* __restrict__ Bp0, const _Float16* __restrict__ Bp1,
        const float* __restrict__ bias,
        float* __restrict__ O1,
        _Float16* __restrict__ OH, int N) {
    constexpr int RSA = (LAYER == 1) ? 128 : 256;   // A row stride (halfs)
    __shared__ _Float16 As[128 * 64];   // 16 KiB
    __shared__ _Float16 Bs[256 * 64];   // 32 KiB

    const int m0 = blockIdx.x * 128;
    const int tid = threadIdx.x;
    const int lane = tid & 63;
    const int wid = tid >> 6;           // 0..7
    const int wm = wid >> 2, wn = wid & 3;
    const int lr = lane & 15, lg = lane >> 4;

    // DMA lane geometry: 8 rows x 8 slots x 16 B = 1 KB per issue
    const int r8 = lane >> 3;
    const int scs = lane & 7;
    const int k8s = scs ^ r8;          // pre-swizzled source chunk within 128 B slice

    f32x4 acc[4][4];
#pragma unroll
    for (int i = 0; i < 4; i++)
#pragma unroll
        for (int j = 0; j < 4; j++) acc[i][j] = (f32x4)0.0f;

#pragma unroll
    for (int kt = 0; kt < 4; ++kt) {
        __syncthreads();    // previous stage's readers done
        // ---- STAGE kt: A 16 segs (2/wave), B 32 segs (4/wave) ----
        {
            const _Float16* Asrc;
            int aoffk;
            if constexpr (LAYER == 1) { Asrc = (kt < 2) ? Ap0 : Ap1; aoffk = (kt & 1) * 64; }
            else                      { Asrc = Ap0;                  aoffk = kt * 64; }
#pragma unroll
            for (int it = 0; it < 2; ++it) {
                int seg = wid * 2 + it;          // 0..15
                int row = seg * 8 + r8;          // 0..127
                int gn = m0 + row;
                if (gn < N)
                    gload16(Asrc + (long long)gn * RSA + aoffk + k8s * 8, &As[seg * 512]);
            }
#pragma unroll
            for (int it = 0; it < 4; ++it) {
                int seg = wid * 4 + it;          // 0..31
                int row = seg * 8 + r8;          // 0..255 (output col)
                const _Float16* Bsrc;
                long long boff;
                if constexpr (LAYER == 1) {
                    Bsrc = (kt < 2) ? Bp0 : Bp1;             // W1l / W1r, rows 0..255
                    boff = (long long)row * 128 + (kt & 1) * 64;
                } else {
                    Bsrc = (row < 128) ? Bp0 : Bp1;          // W2l / W2r
                    boff = (long long)(row & 127) * 256 + kt * 64;
                }
                gload16(Bsrc + boff + k8s * 8, &Bs[seg * 512]);
            }
        }
        __syncthreads();    // drain DMA: stage kt ready

        // ---- COMPUTE: 2 k-steps of 32 ----
#pragma unroll
        for (int ks = 0; ks < 2; ++ks) {
            const int c = ks * 4 + lg;           // k-chunk 0..7
            f16x8 bf[4];
#pragma unroll
            for (int fc = 0; fc < 4; ++fc) {
                int c_ = wn * 64 + fc * 16 + lr;             // 0..255
                bf[fc] = *(const f16x8*)&Bs[c_ * 64 + (c ^ (c_ & 7)) * 8];
            }
#pragma unroll
            for (int fr = 0; fr < 4; ++fr) {
                int r_ = wm * 64 + fr * 16 + lr;             // 0..127
                f16x8 af = *(const f16x8*)&As[r_ * 64 + (c ^ (r_ & 7)) * 8];
#pragma unroll
                for (int fc = 0; fc < 4; ++fc)
                    acc[fr][fc] = __builtin_amdgcn_mfma_f32_16x16x32_f16(af, bf[fc], acc[fr][fc], 0, 0, 0);
            }
        }
    }

    // ---- epilogue: C/D map col=lane&15, row=(lane>>4)*4+reg ----
    if constexpr (LAYER == 1) {
#pragma unroll
        for (int fc = 0; fc < 4; ++fc) {
            int col = wn * 64 + fc * 16 + lr;       // 0..255
            float bv = bias[col];
#pragma unroll
            for (int fr = 0; fr < 4; ++fr) {
#pragma unroll
                for (int j = 0; j < 4; ++j) {
                    int row = m0 + wm * 64 + fr * 16 + lg * 4 + j;
                    if (row < N)
                        OH[(long long)row * 256 + col] =
                            (_Float16)fmaxf(acc[fr][fc][j] + bv, 0.0f);
                }
            }
        }
    } else {
#pragma unroll
        for (int fc = 0; fc < 4; ++fc) {
            int col = wn * 64 + fc * 16 + lr;       // 0..255
#pragma unroll
            for (int fr = 0; fr < 4; ++fr) {
#pragma unroll
                for (int j = 0; j < 4; ++j) {
                    int row = m0 + wm * 64 + fr * 16 + lg * 4 + j;
                    if (row < N) {
                        if (col < 128)
                            OH[(long long)row * 128 + col] = (_Float16)acc[fr][fc][j];
                        else
                            O1[(long long)row * 128 + (col - 128)] = acc[fr][fc][j];
                    }
                }
            }
        }
    }
}

extern "C" void kernel_launch(void* const* d_in, const int* in_sizes, int n_in,
                              void* d_out, int out_size, void* d_ws, size_t ws_size,
                              hipStream_t stream) {
    const float* x   = (const float*)d_in[0];
    const int*   ei  = (const int*)d_in[1];     // [2, E]
    const float* W1l = (const float*)d_in[2];
    const float* b1l = (const float*)d_in[3];
    const float* W1r = (const float*)d_in[4];
    const float* W2l = (const float*)d_in[5];
    const float* b2l = (const float*)d_in[6];
    const float* W2r = (const float*)d_in[7];
    float* out = (float*)d_out;

    const int N = N_NODES, E = N_EDGES;
    const int* srcI = ei;
    const int* dstI = ei + E;

    char* ws = (char*)d_ws;
    size_t off = 0;
    auto alloc = [&](size_t bytes) {
        size_t o = off;
        off += (bytes + 511) & ~(size_t)511;
        return o;
    };
    size_t off_cnt   = alloc((size_t)N * 4);
    size_t off_offs  = alloc((size_t)(N + 1) * 4);
    size_t off_cur   = alloc((size_t)N * 4);
    size_t off_bsum  = alloc((size_t)SCAN_NB * 4);
    size_t off_boff  = alloc((size_t)SCAN_NB * 4);
    size_t off_perm  = alloc((size_t)E * 4);
    size_t off_x16   = alloc((size_t)N * 128 * 2);     // x f16
    size_t off_m16   = alloc((size_t)N * 128 * 2);     // mean f16
    size_t off_h16   = alloc((size_t)N * 256 * 2);     // h f16
    size_t off_g16   = alloc((size_t)N * 128 * 2);     // g f16
    size_t off_r2    = alloc((size_t)N * 128 * 4);     // fp32
    size_t off_w     = alloc((size_t)4 * 32768 * 2);   // 4 f16 weights
    int*      cntI = (int*)(ws + off_cnt);
    int*      offs = (int*)(ws + off_offs);
    int*      cur  = (int*)(ws + off_cur);
    int*      bsum = (int*)(ws + off_bsum);
    int*      boff = (int*)(ws + off_boff);
    int*      perm = (int*)(ws + off_perm);
    _Float16* x16  = (_Float16*)(ws + off_x16);
    _Float16* m16  = (_Float16*)(ws + off_m16);
    _Float16* h16  = (_Float16*)(ws + off_h16);
    _Float16* g16  = (_Float16*)(ws + off_g16);
    float*    r2   = (float*)(ws + off_r2);
    _Float16* wbuf = (_Float16*)(ws + off_w);
    const int WSZ = 32768;                             // 256*128 elems
    _Float16* w1l16 = wbuf;            _Float16* w1r16 = wbuf + WSZ;
    _Float16* w2l16 = wbuf + 2 * WSZ;  _Float16* w2r16 = wbuf + 3 * WSZ;

    // ---- CSR build ----
    (void)hipMemsetAsync(cntI, 0, (size_t)N * 4, stream);
    count_int_k<<<(E + 255) / 256, 256, 0, stream>>>(dstI, cntI, E);
    scan1_k<<<SCAN_NB, 256, 0, stream>>>(cntI, offs, bsum, N);
    scan2_k<<<1, 256, 0, stream>>>(bsum, boff, SCAN_NB);
    scan3_k<<<(N + 255) / 256, 256, 0, stream>>>(offs, cur, boff, N, E);
    fill_k<<<(E + 255) / 256, 256, 0, stream>>>(srcI, dstI, cur, perm, E);

    // ---- f16 conversions ----
    {
        int n8x = N * 16;                          // N*128/8
        cvt_f16_k<<<(n8x + 255) / 256, 256, 0, stream>>>(x, x16, n8x);
        int n8w = 32768 / 8;                       // 4096
        cvt_f16_k<<<(n8w + 255) / 256, 256, 0, stream>>>(W1l, w1l16, n8w);
        cvt_f16_k<<<(n8w + 255) / 256, 256, 0, stream>>>(W1r, w1r16, n8w);
        cvt_f16_k<<<(n8w + 255) / 256, 256, 0, stream>>>(W2l, w2l16, n8w);
        cvt_f16_k<<<(n8w + 255) / 256, 256, 0, stream>>>(W2r, w2r16, n8w);
    }

    // ---- layer 1 ----
    aggmean_k<<<(N + 7) / 8, 256, 0, stream>>>(x16, perm, offs, m16, N);
    {
        int nblk = (N + 127) / 128;
        gemm_mfma_k<1><<<nblk, 512, 0, stream>>>(m16, x16, w1l16, w1r16,
                                                 b1l, nullptr, h16, N);
    }

    // ---- layer 2 ----
    {
        int nblk = (N + 127) / 128;
        gemm_mfma_k<2><<<nblk, 512, 0, stream>>>(h16, h16, w2l16, w2r16,
                                                 nullptr, r2, g16, N);
    }
    aggout_k<<<(N + 7) / 8, 256, 0, stream>>>(g16, perm, offs, r2, b2l, out, N);
}